// Round 7
// baseline (427.942 us; speedup 1.0000x reference)
//
#include <hip/hip_runtime.h>
#include <math.h>

#define NB 4
#define NC 256
#define NCI 128
#define NC2 512
#define NPOS 4096
#define ISPLIT 8

using bf16x8 = __attribute__((ext_vector_type(8))) short;
using f32x4  = __attribute__((ext_vector_type(4))) float;

__device__ inline unsigned short f2bf(float f) {
  unsigned int u = __float_as_uint(f);
  u = (u + 0x7fffu + ((u >> 16) & 1u)) >> 16;
  return (unsigned short)u;
}
__device__ inline float bf2f(short s) {
  return __uint_as_float(((unsigned int)(unsigned short)s) << 16);
}

// ---------------- cast 4 weight tensors fp32 -> bf16 ----------------
__global__ void k_cast4(const float* __restrict__ s0, short* __restrict__ d0, int n0,
                        const float* __restrict__ s1, short* __restrict__ d1, int n1,
                        const float* __restrict__ s2, short* __restrict__ d2, int n2,
                        const float* __restrict__ s3, short* __restrict__ d3, int n3) {
  int i = blockIdx.x * 256 + threadIdx.x;
  if (i < n0) { d0[i] = (short)f2bf(s0[i]); return; } i -= n0;
  if (i < n1) { d1[i] = (short)f2bf(s1[i]); return; } i -= n1;
  if (i < n2) { d2[i] = (short)f2bf(s2[i]); return; } i -= n2;
  if (i < n3) { d3[i] = (short)f2bf(s3[i]); }
}

// ---------------- transpose-cast: in [b][R][C] f32 -> out [b][C][R] bf16 -------
__global__ __launch_bounds__(256) void k_tcast(
    const float* __restrict__ in, short* __restrict__ out,
    int R, int C, size_t inBs, size_t outBs) {
  __shared__ float t[64][65];
  const int tid = threadIdx.x;
  const int r0 = blockIdx.y * 64, c0 = blockIdx.x * 64, b = blockIdx.z;
  {
    int r = tid >> 2, cc = (tid & 3) * 16;
    const float* ib = in + (size_t)b * inBs + (size_t)(r0 + r) * C + c0 + cc;
#pragma unroll
    for (int i = 0; i < 4; ++i) {
      float4 v = *(const float4*)(ib + i * 4);
      t[r][cc + i * 4 + 0] = v.x; t[r][cc + i * 4 + 1] = v.y;
      t[r][cc + i * 4 + 2] = v.z; t[r][cc + i * 4 + 3] = v.w;
    }
  }
  __syncthreads();
  {
    int c = tid >> 2, rr = (tid & 3) * 16;
    __align__(16) short v[16];
#pragma unroll
    for (int i = 0; i < 16; ++i) v[i] = (short)f2bf(t[rr + i][c]);
    short* ob = out + (size_t)b * outBs + (size_t)(c0 + c) * R + r0 + rr;
    *(int4*)(ob) = *(const int4*)(v);
    *(int4*)(ob + 8) = *(const int4*)(v + 8);
  }
}

// ---------------- sum 4 bf16 partials [p][b][cc][i] -> transpose [b][i][cc] bf16
__global__ __launch_bounds__(256) void k_tcast4(
    const short* __restrict__ inP, short* __restrict__ out) {
  __shared__ float t[64][65];
  const int tid = threadIdx.x;
  const int r0 = blockIdx.y * 64, c0 = blockIdx.x * 64, b = blockIdx.z;
  {
    int r = tid >> 2, cc = (tid & 3) * 16;
    float tacc[16] = {};
#pragma unroll
    for (int p = 0; p < 4; ++p) {
      const short* ib = inP + ((size_t)p * NB + b) * NC * NPOS +
                        (size_t)(r0 + r) * NPOS + c0 + cc;
      bf16x8 a = *(const bf16x8*)(ib);
      bf16x8 a2 = *(const bf16x8*)(ib + 8);
#pragma unroll
      for (int i = 0; i < 8; ++i) { tacc[i] += bf2f(a[i]); tacc[8 + i] += bf2f(a2[i]); }
    }
#pragma unroll
    for (int i = 0; i < 16; ++i) t[r][cc + i] = tacc[i];
  }
  __syncthreads();
  {
    int c = tid >> 2, rr = (tid & 3) * 16;
    __align__(16) short v[16];
#pragma unroll
    for (int i = 0; i < 16; ++i) v[i] = (short)f2bf(t[rr + i][c]);
    short* ob = out + (size_t)b * (size_t)NPOS * NC + (size_t)(c0 + c) * NC + r0 + rr;
    *(int4*)(ob) = *(const int4*)(v);
    *(int4*)(ob + 8) = *(const int4*)(v + 8);
  }
}

// ---------------- generic bf16 MFMA GEMM ----------------
template<bool OUT_BF16, bool HAS_RES>
__global__ __launch_bounds__(256, 2) void k_gemm(
    const short* __restrict__ A, const short* __restrict__ B,
    void* __restrict__ outv, const float* __restrict__ res,
    int K, int sN, size_t aBs, size_t bBs, size_t oBs) {
  __shared__ short As[2][64 * 64];
  __shared__ short Bs_[2][64 * 64];
  const int tid = threadIdx.x, lane = tid & 63, w = tid >> 6;
  const int x = lane & 15, q = lane >> 4;
  const int wm = (w & 1) * 32, wn = (w >> 1) * 32;
  const int n0 = blockIdx.x * 64, m0 = blockIdx.y * 64, b = blockIdx.z;
  const short* Ab = A + (size_t)b * aBs + (size_t)m0 * K;
  const short* Bb = B + (size_t)b * bBs + (size_t)n0 * K;
  const int r = tid >> 2, cth = tid & 3;
  f32x4 acc[2][2];
  acc[0][0] = acc[0][1] = acc[1][0] = acc[1][1] = (f32x4){0.f, 0.f, 0.f, 0.f};
  int4 ra[2], rb[2];
  const int NK = K >> 6;
#define GLOAD(kt)                                                              \
  { _Pragma("unroll") for (int i = 0; i < 2; ++i) {                            \
      ra[i] = *(const int4*)(Ab + (size_t)r * K + (kt) * 64 + (cth + i * 4) * 8); \
      rb[i] = *(const int4*)(Bb + (size_t)r * K + (kt) * 64 + (cth + i * 4) * 8); } }
#define GWRITE(buf)                                                            \
  { _Pragma("unroll") for (int i = 0; i < 2; ++i) {                            \
      *(int4*)(&As[buf][r * 64 + (((cth + i * 4) ^ (r & 7)) * 8)]) = ra[i];    \
      *(int4*)(&Bs_[buf][r * 64 + (((cth + i * 4) ^ (r & 7)) * 8)]) = rb[i]; } }
  GLOAD(0); GWRITE(0); __syncthreads();
  int cur = 0;
  for (int kt = 0; kt < NK; ++kt) {
    if (kt + 1 < NK) GLOAD(kt + 1);
    bf16x8 af[2][2], bfr[2][2];
#pragma unroll
    for (int ms = 0; ms < 2; ++ms) {
      int rowm = wm + ms * 16 + x;
#pragma unroll
      for (int ks = 0; ks < 2; ++ks)
        af[ms][ks] = *(const bf16x8*)(&As[cur][rowm * 64 + (((ks * 4 + q) ^ (rowm & 7)) * 8)]);
    }
#pragma unroll
    for (int ns = 0; ns < 2; ++ns) {
      int rown = wn + ns * 16 + x;
#pragma unroll
      for (int ks = 0; ks < 2; ++ks)
        bfr[ns][ks] = *(const bf16x8*)(&Bs_[cur][rown * 64 + (((ks * 4 + q) ^ (rown & 7)) * 8)]);
    }
#pragma unroll
    for (int ms = 0; ms < 2; ++ms)
#pragma unroll
      for (int ns = 0; ns < 2; ++ns)
#pragma unroll
        for (int ks = 0; ks < 2; ++ks)
          acc[ms][ns] = __builtin_amdgcn_mfma_f32_16x16x32_bf16(
              af[ms][ks], bfr[ns][ks], acc[ms][ns], 0, 0, 0);
    if (kt + 1 < NK) GWRITE(cur ^ 1);
    __syncthreads();
    cur ^= 1;
  }
#pragma unroll
  for (int ms = 0; ms < 2; ++ms)
#pragma unroll
    for (int ns = 0; ns < 2; ++ns) {
      int n = n0 + wn + ns * 16 + x;
      int m = m0 + wm + ms * 16 + q * 4;
      size_t off = (size_t)b * oBs + (size_t)n * sN + m;
      if (OUT_BF16) {
        __align__(8) short pv[4];
#pragma unroll
        for (int j = 0; j < 4; ++j) pv[j] = (short)f2bf(acc[ms][ns][j]);
        *(uint2*)((short*)outv + off) = *(const uint2*)pv;
      } else {
        float4 v = {acc[ms][ns][0], acc[ms][ns][1], acc[ms][ns][2], acc[ms][ns][3]};
        if (HAS_RES) {
          float4 rv = *(const float4*)(res + off);
          v.x += rv.x; v.y += rv.y; v.z += rv.z; v.w += rv.w;
        }
        *(float4*)((float*)outv + off) = v;
      }
    }
#undef GLOAD
#undef GWRITE
}

// ---------------- partial l[j]: plsum[b][iy][j] = sum_{i in chunk} exp(s[i][j]) ----
__global__ __launch_bounds__(256, 4) void k_lsum(
    const short* __restrict__ phiB, const short* __restrict__ thetaB,
    float* __restrict__ plsum) {
  __shared__ short thT[2][64 * 128];
  const int tid = threadIdx.x, lane = tid & 63, w = tid >> 6;
  const int x = lane & 15, q = lane >> 4;
  const int j0 = blockIdx.x * 64, iy = blockIdx.y, b = blockIdx.z;
  const short* phb = phiB + (size_t)b * NPOS * NCI;
  const short* thb = thetaB + (size_t)b * NPOS * NCI + (size_t)iy * (NPOS / ISPLIT) * NCI;
  bf16x8 af[4];
  {
    const short* pr = phb + (size_t)(j0 + w * 16 + x) * NCI;
#pragma unroll
    for (int kk = 0; kk < 4; ++kk) af[kk] = *(const bf16x8*)(pr + kk * 32 + q * 8);
  }
  float lsum[4] = {0.f, 0.f, 0.f, 0.f};
  int4 rt[4];
  const int NIT = NPOS / ISPLIT / 64;   // 8
#define LSUM_LOAD(it)                                                         \
  { _Pragma("unroll") for (int r = 0; r < 4; ++r) {                           \
      int s = tid + r * 256; int row = s >> 4, c = s & 15;                    \
      rt[r] = *(const int4*)(thb + (size_t)((it) * 64 + row) * NCI + c * 8); } }
#define LSUM_WRITE(buf)                                                       \
  { _Pragma("unroll") for (int r = 0; r < 4; ++r) {                           \
      int s = tid + r * 256; int row = s >> 4, c = s & 15;                    \
      *(int4*)(&thT[buf][row * 128 + ((c ^ (row & 7)) * 8)]) = rt[r]; } }
  LSUM_LOAD(0); LSUM_WRITE(0); __syncthreads();
  int cur = 0;
  for (int it = 0; it < NIT; ++it) {
    if (it + 1 < NIT) LSUM_LOAD(it + 1);
#pragma unroll
    for (int ii = 0; ii < 4; ++ii) {
      f32x4 s = {0.f, 0.f, 0.f, 0.f};
      int row = ii * 16 + x;
      int sw = row & 7;
#pragma unroll
      for (int kk = 0; kk < 4; ++kk) {
        bf16x8 bfv = *(const bf16x8*)(&thT[cur][row * 128 + (((kk * 4 + q) ^ sw) * 8)]);
        s = __builtin_amdgcn_mfma_f32_16x16x32_bf16(af[kk], bfv, s, 0, 0, 0);
      }
#pragma unroll
      for (int r = 0; r < 4; ++r) lsum[r] += __expf(s[r]);
    }
    if (it + 1 < NIT) LSUM_WRITE(cur ^ 1);
    __syncthreads();
    cur ^= 1;
  }
#pragma unroll
  for (int m = 1; m < 16; m <<= 1)
#pragma unroll
    for (int r = 0; r < 4; ++r) lsum[r] += __shfl_xor(lsum[r], m);
  if (x == 0) {
#pragma unroll
    for (int r = 0; r < 4; ++r)
      plsum[((size_t)(b * ISPLIT + iy) << 12) + j0 + w * 16 + 4 * q + r] = lsum[r];
  }
#undef LSUM_LOAD
#undef LSUM_WRITE
}

// ---------------- combine partials -> linv ----------------
__global__ void k_lcomb(const float* __restrict__ plsum, float* __restrict__ linv) {
  int i = blockIdx.x * 256 + threadIdx.x;   // NB*NPOS
  int b = i >> 12, j = i & (NPOS - 1);
  float s = 0.f;
#pragma unroll
  for (int t = 0; t < ISPLIT; ++t) s += plsum[((size_t)(b * ISPLIT + t) << 12) + j];
  linv[i] = 1.0f / s;
}

// ---------------- fold linv into g: gB[cc][p] *= linv[p] ----------------
__global__ void k_scale_g(short* __restrict__ gB, const float* __restrict__ linv) {
  size_t e = ((size_t)blockIdx.x * 256 + threadIdx.x) * 8;
  int b = (int)(e >> 20);
  int p = (int)(e & (NPOS - 1));
  __align__(16) short v[8];
  *(int4*)v = *(const int4*)(gB + e);
  const float* lv = linv + ((size_t)b << 12) + p;
#pragma unroll
  for (int k = 0; k < 8; ++k) v[k] = (short)f2bf(bf2f(v[k]) * lv[k]);
  *(int4*)(gB + e) = *(const int4*)v;
}

// ---------------- attention with wave role-split ----------------
// Block: 64 i rows x full cc, j-quarter (1024 j = 32 tiles of 32).
// S^T: wave (jsub=w&1, ih=w>>1) computes 16j x 32i quadrant -> shared pT.
// PV: wave w owns cc-quarter (64 cc) x all 64 i.
__global__ __launch_bounds__(256, 3) void k_attn(
    const short* __restrict__ phiB, const short* __restrict__ thetaB,
    const short* __restrict__ gB, short* __restrict__ omidP) {
  __shared__ short phiT[2][32 * 128];   // 8KB each
  __shared__ short gT[2][256 * 32];     // 16KB each
  __shared__ short pT[64 * 32];         // 4KB shared P tile [i][j]
  const int tid = threadIdx.x, lane = tid & 63, w = tid >> 6;
  const int x = lane & 15, q = lane >> 4;
  const int jsub = w & 1, ih = w >> 1;
  const int i0 = blockIdx.x * 64, jq = blockIdx.y, b = blockIdx.z;
  const short* phb = phiB + (size_t)b * NPOS * NCI;
  const short* thb = thetaB + (size_t)b * NPOS * NCI;
  const short* gb = gB + (size_t)b * NC * NPOS;
  short* om = omidP + ((size_t)(jq * NB + b)) * NC * NPOS;

  // theta B-frags for this wave's i-half: i = i0 + ih*32 + f*16 + x
  bf16x8 tf[2][4];
#pragma unroll
  for (int f = 0; f < 2; ++f) {
    const short* tr = thb + (size_t)(i0 + ih * 32 + f * 16 + x) * NCI;
#pragma unroll
    for (int kk = 0; kk < 4; ++kk) tf[f][kk] = *(const bf16x8*)(tr + kk * 32 + q * 8);
  }
  f32x4 acc[4][4];   // [if][cfl]
#pragma unroll
  for (int i = 0; i < 4; ++i)
#pragma unroll
    for (int j = 0; j < 4; ++j) acc[i][j] = (f32x4){0.f, 0.f, 0.f, 0.f};

  const int sx = (x >> 1) & 3;                 // pT swizzle key
  const int sgx = (x & 3) ^ ((x >> 2) & 1);    // gT read swizzle key
  int4 rphi[2], rg[4];
  const int NT = 32;
  const int JT0 = jq * 32;
#define ATTN_LOAD(jt)                                                          \
  { _Pragma("unroll") for (int r = 0; r < 2; ++r) {                            \
      int s = tid + r * 256; int row = s >> 4, c = s & 15;                     \
      rphi[r] = *(const int4*)(phb + (size_t)((JT0 + (jt)) * 32 + row) * NCI + c * 8); } \
    _Pragma("unroll") for (int r = 0; r < 4; ++r) {                            \
      int s = tid + r * 256; int cc = s >> 2, c4 = s & 3;                      \
      rg[r] = *(const int4*)(gb + (size_t)cc * NPOS + (JT0 + (jt)) * 32 + c4 * 8); } }
#define ATTN_WRITE(buf)                                                        \
  { _Pragma("unroll") for (int r = 0; r < 2; ++r) {                            \
      int s = tid + r * 256; int row = s >> 4, c = s & 15;                     \
      *(int4*)(&phiT[buf][row * 128 + ((c ^ (row & 7)) * 8)]) = rphi[r]; }     \
    _Pragma("unroll") for (int r = 0; r < 4; ++r) {                            \
      int s = tid + r * 256; int cc = s >> 2, c4 = s & 3;                      \
      int sw = (cc & 3) ^ ((cc >> 2) & 1);                                     \
      *(int4*)(&gT[buf][cc * 32 + ((c4 ^ sw) * 8)]) = rg[r]; } }
  ATTN_LOAD(0); ATTN_WRITE(0); __syncthreads();
  int cur = 0;
  for (int jt = 0; jt < NT; ++jt) {
    if (jt + 1 < NT) ATTN_LOAD(jt + 1);
    const short* PH = &phiT[cur][0];
    const short* GT = &gT[cur][0];
    // S^T quadrant: rows j = jsub*16 + x (A), cols i = ih*32 + f*16 (B=tf)
    {
      int row = jsub * 16 + x;
      int swr = row & 7;
#pragma unroll
      for (int f = 0; f < 2; ++f) {
        f32x4 s = {0.f, 0.f, 0.f, 0.f};
#pragma unroll
        for (int kk = 0; kk < 4; ++kk) {
          bf16x8 a = *(const bf16x8*)(PH + row * 128 + (((kk * 4 + q) ^ swr) * 8));
          s = __builtin_amdgcn_mfma_f32_16x16x32_bf16(a, tf[f][kk], s, 0, 0, 0);
        }
        // lane holds S^T[j=jsub*16+4q+r][i=ih*32+f*16+x]
        unsigned short p0 = f2bf(__expf(s[0]));
        unsigned short p1 = f2bf(__expf(s[1]));
        unsigned short p2 = f2bf(__expf(s[2]));
        unsigned short p3 = f2bf(__expf(s[3]));
        unsigned int lo = (unsigned int)p0 | ((unsigned int)p1 << 16);
        unsigned int hi = (unsigned int)p2 | ((unsigned int)p3 << 16);
        int irow = ih * 32 + f * 16 + x;
        int byteoff = (irow * 64 + jsub * 32 + q * 8) ^ (sx << 4);
        *(uint2*)((char*)pT + byteoff) = make_uint2(lo, hi);
      }
    }
    __syncthreads();   // pT ready for cross-wave PV reads
    {
      bf16x8 ap[4];
#pragma unroll
      for (int f = 0; f < 4; ++f)
        ap[f] = *(const bf16x8*)((const char*)pT + (f * 16 + x) * 64 + ((q ^ sx) * 16));
#pragma unroll
      for (int cfl = 0; cfl < 4; ++cfl) {
        int row = w * 64 + cfl * 16 + x;
        bf16x8 bg = *(const bf16x8*)(GT + row * 32 + ((q ^ sgx) * 8));
#pragma unroll
        for (int f = 0; f < 4; ++f)
          acc[f][cfl] = __builtin_amdgcn_mfma_f32_16x16x32_bf16(ap[f], bg, acc[f][cfl], 0, 0, 0);
      }
    }
    if (jt + 1 < NT) ATTN_WRITE(cur ^ 1);
    __syncthreads();   // protects pT overwrite + staging buffer swap
    cur ^= 1;
  }
  // store: D[i=4q+r][cc=x] per (if, cfl); om is bf16 [cc][i]
#pragma unroll
  for (int f = 0; f < 4; ++f)
#pragma unroll
    for (int cfl = 0; cfl < 4; ++cfl) {
      __align__(8) short pv[4];
#pragma unroll
      for (int j = 0; j < 4; ++j) pv[j] = (short)f2bf(acc[f][cfl][j]);
      size_t o = (size_t)(w * 64 + cfl * 16 + x) * NPOS + i0 + f * 16 + 4 * q;
      *(uint2*)(om + o) = *(const uint2*)pv;
    }
#undef ATTN_LOAD
#undef ATTN_WRITE
}

extern "C" void kernel_launch(void* const* d_in, const int* in_sizes, int n_in,
                              void* d_out, int out_size, void* d_ws, size_t ws_size,
                              hipStream_t stream) {
  (void)in_sizes; (void)n_in; (void)out_size; (void)ws_size;
  const float* x0      = (const float*)d_in[0];
  const float* x       = (const float*)d_in[1];
  const float* x_dsm   = (const float*)d_in[2];
  const float* w_phi   = (const float*)d_in[3];
  const float* w_theta = (const float*)d_in[4];
  const float* w_g     = (const float*)d_in[5];
  const float* w_mask  = (const float*)d_in[6];
  float* outp = (float*)d_out;

  short* sp = (short*)d_ws;
  short* wb_phi   = sp; sp += 32768;
  short* wb_theta = sp; sp += 32768;
  short* wb_g     = sp; sp += 131072;
  short* wb_mask  = sp; sp += 131072;
  short* xT   = sp; sp += (size_t)NB * NPOS * NC;          // 8MB
  short* xdT  = sp; sp += (size_t)NB * NPOS * NC;          // 8MB
  short* x0T  = sp; sp += (size_t)NB * NPOS * NC2;         // 16MB
  short* phiB   = sp; sp += (size_t)NB * NPOS * NCI;       // 4MB
  short* thetaB = sp; sp += (size_t)NB * NPOS * NCI;       // 4MB
  short* gBuf   = sp; sp += (size_t)NB * NC * NPOS;        // 8MB
  float* linv = (float*)sp; sp += 2 * (size_t)NB * NPOS;
  float* plsum = (float*)sp;                               // [b][ISPLIT][NPOS]
  short* omidP = xT;       // 4 bf16 partials x 8MB = 32MB, aliases xT/xdT/x0T
  short* omidT = phiB;     // 8MB bf16 [b][p][cc], aliases phiB/thetaB

  k_cast4<<<dim3(1280), 256, 0, stream>>>(w_phi, wb_phi, 32768,
                                          w_theta, wb_theta, 32768,
                                          w_g, wb_g, 131072,
                                          w_mask, wb_mask, 131072);

  k_tcast<<<dim3(64, 4, NB), 256, 0, stream>>>(x, xT, NC, NPOS,
      (size_t)NC * NPOS, (size_t)NPOS * NC);
  k_tcast<<<dim3(64, 4, NB), 256, 0, stream>>>(x_dsm, xdT, NC, NPOS,
      (size_t)NC * NPOS, (size_t)NPOS * NC);
  k_tcast<<<dim3(64, 8, NB), 256, 0, stream>>>(x0, x0T, NC2, NPOS,
      (size_t)NC2 * NPOS, (size_t)NPOS * NC2);

  k_gemm<true, false><<<dim3(64, 2, NB), 256, 0, stream>>>(
      wb_phi, xT, phiB, nullptr, NC, NCI, 0, (size_t)NPOS * NC, (size_t)NPOS * NCI);
  k_gemm<true, false><<<dim3(64, 2, NB), 256, 0, stream>>>(
      wb_theta, xdT, thetaB, nullptr, NC, NCI, 0, (size_t)NPOS * NC, (size_t)NPOS * NCI);
  k_gemm<true, false><<<dim3(4, 64, NB), 256, 0, stream>>>(
      x0T, wb_g, gBuf, nullptr, NC2, NPOS, (size_t)NPOS * NC2, 0, (size_t)NC * NPOS);

  k_lsum<<<dim3(NPOS / 64, ISPLIT, NB), 256, 0, stream>>>(phiB, thetaB, plsum);
  k_lcomb<<<dim3(NB * NPOS / 256), 256, 0, stream>>>(plsum, linv);
  k_scale_g<<<dim3(2048), 256, 0, stream>>>(gBuf, linv);

  k_attn<<<dim3(64, 4, NB), 256, 0, stream>>>(phiB, thetaB, gBuf, omidP);

  k_tcast4<<<dim3(64, 4, NB), 256, 0, stream>>>(omidP, omidT);

  k_gemm<false, true><<<dim3(8, 64, NB), 256, 0, stream>>>(
      omidT, wb_mask, outp, x0, NC, NPOS, (size_t)NPOS * NC, 0, (size_t)NC2 * NPOS);
}

// Round 8
// 260.786 us; speedup vs baseline: 1.6410x; 1.6410x over previous
//
#include <hip/hip_runtime.h>
#include <math.h>

#define NB 4
#define NC 256
#define NCI 128
#define NC2 512
#define NPOS 4096
#define ISPLIT 8

using bf16x8 = __attribute__((ext_vector_type(8))) short;
using f32x4  = __attribute__((ext_vector_type(4))) float;

__device__ inline unsigned short f2bf(float f) {
  unsigned int u = __float_as_uint(f);
  u = (u + 0x7fffu + ((u >> 16) & 1u)) >> 16;
  return (unsigned short)u;
}
__device__ inline float bf2f(short s) {
  return __uint_as_float(((unsigned int)(unsigned short)s) << 16);
}

// ---------------- cast 4 weight tensors fp32 -> bf16 ----------------
__global__ void k_cast4(const float* __restrict__ s0, short* __restrict__ d0, int n0,
                        const float* __restrict__ s1, short* __restrict__ d1, int n1,
                        const float* __restrict__ s2, short* __restrict__ d2, int n2,
                        const float* __restrict__ s3, short* __restrict__ d3, int n3) {
  int i = blockIdx.x * 256 + threadIdx.x;
  if (i < n0) { d0[i] = (short)f2bf(s0[i]); return; } i -= n0;
  if (i < n1) { d1[i] = (short)f2bf(s1[i]); return; } i -= n1;
  if (i < n2) { d2[i] = (short)f2bf(s2[i]); return; } i -= n2;
  if (i < n3) { d3[i] = (short)f2bf(s3[i]); }
}

// ---------------- transpose-cast: in [b][R][C] f32 -> out [b][C][R] bf16 -------
__global__ __launch_bounds__(256) void k_tcast(
    const float* __restrict__ in, short* __restrict__ out,
    int R, int C, size_t inBs, size_t outBs) {
  __shared__ float t[64][65];
  const int tid = threadIdx.x;
  const int r0 = blockIdx.y * 64, c0 = blockIdx.x * 64, b = blockIdx.z;
  {
    int r = tid >> 2, cc = (tid & 3) * 16;
    const float* ib = in + (size_t)b * inBs + (size_t)(r0 + r) * C + c0 + cc;
#pragma unroll
    for (int i = 0; i < 4; ++i) {
      float4 v = *(const float4*)(ib + i * 4);
      t[r][cc + i * 4 + 0] = v.x; t[r][cc + i * 4 + 1] = v.y;
      t[r][cc + i * 4 + 2] = v.z; t[r][cc + i * 4 + 3] = v.w;
    }
  }
  __syncthreads();
  {
    int c = tid >> 2, rr = (tid & 3) * 16;
    __align__(16) short v[16];
#pragma unroll
    for (int i = 0; i < 16; ++i) v[i] = (short)f2bf(t[rr + i][c]);
    short* ob = out + (size_t)b * outBs + (size_t)(c0 + c) * R + r0 + rr;
    *(int4*)(ob) = *(const int4*)(v);
    *(int4*)(ob + 8) = *(const int4*)(v + 8);
  }
}

// same, summing two f32 sources (combines the two j-half partials of omid)
__global__ __launch_bounds__(256) void k_tcast2(
    const float* __restrict__ inA, const float* __restrict__ inB,
    short* __restrict__ out, int R, int C, size_t inBs, size_t outBs) {
  __shared__ float t[64][65];
  const int tid = threadIdx.x;
  const int r0 = blockIdx.y * 64, c0 = blockIdx.x * 64, b = blockIdx.z;
  {
    int r = tid >> 2, cc = (tid & 3) * 16;
    size_t base = (size_t)b * inBs + (size_t)(r0 + r) * C + c0 + cc;
#pragma unroll
    for (int i = 0; i < 4; ++i) {
      float4 va = *(const float4*)(inA + base + i * 4);
      float4 vb = *(const float4*)(inB + base + i * 4);
      t[r][cc + i * 4 + 0] = va.x + vb.x; t[r][cc + i * 4 + 1] = va.y + vb.y;
      t[r][cc + i * 4 + 2] = va.z + vb.z; t[r][cc + i * 4 + 3] = va.w + vb.w;
    }
  }
  __syncthreads();
  {
    int c = tid >> 2, rr = (tid & 3) * 16;
    __align__(16) short v[16];
#pragma unroll
    for (int i = 0; i < 16; ++i) v[i] = (short)f2bf(t[rr + i][c]);
    short* ob = out + (size_t)b * outBs + (size_t)(c0 + c) * R + r0 + rr;
    *(int4*)(ob) = *(const int4*)(v);
    *(int4*)(ob + 8) = *(const int4*)(v + 8);
  }
}

// ---------------- generic bf16 MFMA GEMM ----------------
template<bool OUT_BF16, bool HAS_RES>
__global__ __launch_bounds__(256, 2) void k_gemm(
    const short* __restrict__ A, const short* __restrict__ B,
    void* __restrict__ outv, const float* __restrict__ res,
    int K, int sN, size_t aBs, size_t bBs, size_t oBs) {
  __shared__ short As[2][64 * 64];
  __shared__ short Bs_[2][64 * 64];
  const int tid = threadIdx.x, lane = tid & 63, w = tid >> 6;
  const int x = lane & 15, q = lane >> 4;
  const int wm = (w & 1) * 32, wn = (w >> 1) * 32;
  const int n0 = blockIdx.x * 64, m0 = blockIdx.y * 64, b = blockIdx.z;
  const short* Ab = A + (size_t)b * aBs + (size_t)m0 * K;
  const short* Bb = B + (size_t)b * bBs + (size_t)n0 * K;
  const int r = tid >> 2, cth = tid & 3;
  f32x4 acc[2][2];
  acc[0][0] = acc[0][1] = acc[1][0] = acc[1][1] = (f32x4){0.f, 0.f, 0.f, 0.f};
  int4 ra[2], rb[2];
  const int NK = K >> 6;
#define GLOAD(kt)                                                              \
  { _Pragma("unroll") for (int i = 0; i < 2; ++i) {                            \
      ra[i] = *(const int4*)(Ab + (size_t)r * K + (kt) * 64 + (cth + i * 4) * 8); \
      rb[i] = *(const int4*)(Bb + (size_t)r * K + (kt) * 64 + (cth + i * 4) * 8); } }
#define GWRITE(buf)                                                            \
  { _Pragma("unroll") for (int i = 0; i < 2; ++i) {                            \
      *(int4*)(&As[buf][r * 64 + (((cth + i * 4) ^ (r & 7)) * 8)]) = ra[i];    \
      *(int4*)(&Bs_[buf][r * 64 + (((cth + i * 4) ^ (r & 7)) * 8)]) = rb[i]; } }
  GLOAD(0); GWRITE(0); __syncthreads();
  int cur = 0;
  for (int kt = 0; kt < NK; ++kt) {
    if (kt + 1 < NK) GLOAD(kt + 1);
    bf16x8 af[2][2], bfr[2][2];
#pragma unroll
    for (int ms = 0; ms < 2; ++ms) {
      int rowm = wm + ms * 16 + x;
#pragma unroll
      for (int ks = 0; ks < 2; ++ks)
        af[ms][ks] = *(const bf16x8*)(&As[cur][rowm * 64 + (((ks * 4 + q) ^ (rowm & 7)) * 8)]);
    }
#pragma unroll
    for (int ns = 0; ns < 2; ++ns) {
      int rown = wn + ns * 16 + x;
#pragma unroll
      for (int ks = 0; ks < 2; ++ks)
        bfr[ns][ks] = *(const bf16x8*)(&Bs_[cur][rown * 64 + (((ks * 4 + q) ^ (rown & 7)) * 8)]);
    }
#pragma unroll
    for (int ms = 0; ms < 2; ++ms)
#pragma unroll
      for (int ns = 0; ns < 2; ++ns)
#pragma unroll
        for (int ks = 0; ks < 2; ++ks)
          acc[ms][ns] = __builtin_amdgcn_mfma_f32_16x16x32_bf16(
              af[ms][ks], bfr[ns][ks], acc[ms][ns], 0, 0, 0);
    if (kt + 1 < NK) GWRITE(cur ^ 1);
    __syncthreads();
    cur ^= 1;
  }
#pragma unroll
  for (int ms = 0; ms < 2; ++ms)
#pragma unroll
    for (int ns = 0; ns < 2; ++ns) {
      int n = n0 + wn + ns * 16 + x;
      int m = m0 + wm + ms * 16 + q * 4;
      size_t off = (size_t)b * oBs + (size_t)n * sN + m;
      if (OUT_BF16) {
        __align__(8) short pv[4];
#pragma unroll
        for (int j = 0; j < 4; ++j) pv[j] = (short)f2bf(acc[ms][ns][j]);
        *(uint2*)((short*)outv + off) = *(const uint2*)pv;
      } else {
        float4 v = {acc[ms][ns][0], acc[ms][ns][1], acc[ms][ns][2], acc[ms][ns][3]};
        if (HAS_RES) {
          float4 rv = *(const float4*)(res + off);
          v.x += rv.x; v.y += rv.y; v.z += rv.z; v.w += rv.w;
        }
        *(float4*)((float*)outv + off) = v;
      }
    }
#undef GLOAD
#undef GWRITE
}

// ---------------- partial l[j]: plsum[b][iy][j] = sum_{i in chunk} exp(s[i][j]) ----
__global__ __launch_bounds__(256, 4) void k_lsum(
    const short* __restrict__ phiB, const short* __restrict__ thetaB,
    float* __restrict__ plsum) {
  __shared__ short thT[2][64 * 128];
  const int tid = threadIdx.x, lane = tid & 63, w = tid >> 6;
  const int x = lane & 15, q = lane >> 4;
  const int j0 = blockIdx.x * 64, iy = blockIdx.y, b = blockIdx.z;
  const short* phb = phiB + (size_t)b * NPOS * NCI;
  const short* thb = thetaB + (size_t)b * NPOS * NCI + (size_t)iy * (NPOS / ISPLIT) * NCI;
  bf16x8 af[4];
  {
    const short* pr = phb + (size_t)(j0 + w * 16 + x) * NCI;
#pragma unroll
    for (int kk = 0; kk < 4; ++kk) af[kk] = *(const bf16x8*)(pr + kk * 32 + q * 8);
  }
  float lsum[4] = {0.f, 0.f, 0.f, 0.f};
  int4 rt[4];
  const int NIT = NPOS / ISPLIT / 64;   // 8
#define LSUM_LOAD(it)                                                         \
  { _Pragma("unroll") for (int r = 0; r < 4; ++r) {                           \
      int s = tid + r * 256; int row = s >> 4, c = s & 15;                    \
      rt[r] = *(const int4*)(thb + (size_t)((it) * 64 + row) * NCI + c * 8); } }
#define LSUM_WRITE(buf)                                                       \
  { _Pragma("unroll") for (int r = 0; r < 4; ++r) {                           \
      int s = tid + r * 256; int row = s >> 4, c = s & 15;                    \
      *(int4*)(&thT[buf][row * 128 + ((c ^ (row & 7)) * 8)]) = rt[r]; } }
  LSUM_LOAD(0); LSUM_WRITE(0); __syncthreads();
  int cur = 0;
  for (int it = 0; it < NIT; ++it) {
    if (it + 1 < NIT) LSUM_LOAD(it + 1);
#pragma unroll
    for (int ii = 0; ii < 4; ++ii) {
      f32x4 s = {0.f, 0.f, 0.f, 0.f};
      int row = ii * 16 + x;
      int sw = row & 7;
#pragma unroll
      for (int kk = 0; kk < 4; ++kk) {
        bf16x8 bfv = *(const bf16x8*)(&thT[cur][row * 128 + (((kk * 4 + q) ^ sw) * 8)]);
        s = __builtin_amdgcn_mfma_f32_16x16x32_bf16(af[kk], bfv, s, 0, 0, 0);
      }
#pragma unroll
      for (int r = 0; r < 4; ++r) lsum[r] += __expf(s[r]);
    }
    if (it + 1 < NIT) LSUM_WRITE(cur ^ 1);
    __syncthreads();
    cur ^= 1;
  }
#pragma unroll
  for (int m = 1; m < 16; m <<= 1)
#pragma unroll
    for (int r = 0; r < 4; ++r) lsum[r] += __shfl_xor(lsum[r], m);
  if (x == 0) {
#pragma unroll
    for (int r = 0; r < 4; ++r)
      plsum[((size_t)(b * ISPLIT + iy) << 12) + j0 + w * 16 + 4 * q + r] = lsum[r];
  }
#undef LSUM_LOAD
#undef LSUM_WRITE
}

// ---------------- combine partials -> linv ----------------
__global__ void k_lcomb(const float* __restrict__ plsum, float* __restrict__ linv) {
  int i = blockIdx.x * 256 + threadIdx.x;   // NB*NPOS
  int b = i >> 12, j = i & (NPOS - 1);
  float s = 0.f;
#pragma unroll
  for (int t = 0; t < ISPLIT; ++t) s += plsum[((size_t)(b * ISPLIT + t) << 12) + j];
  linv[i] = 1.0f / s;
}

// ---------------- fold linv into g: gB[cc][p] *= linv[p] ----------------
__global__ void k_scale_g(short* __restrict__ gB, const float* __restrict__ linv) {
  size_t e = ((size_t)blockIdx.x * 256 + threadIdx.x) * 8;
  int b = (int)(e >> 20);
  int p = (int)(e & (NPOS - 1));
  __align__(16) short v[8];
  *(int4*)v = *(const int4*)(gB + e);
  const float* lv = linv + ((size_t)b << 12) + p;
#pragma unroll
  for (int k = 0; k < 8; ++k) v[k] = (short)f2bf(bf2f(v[k]) * lv[k]);
  *(int4*)(gB + e) = *(const int4*)v;
}

// ---------------- attention: omidP[jh][b][cc][i] = sum_{j in half} P*g' -------
// R6 structure (lockstep waves, per-wave pT) + conflict-free gT layout
// gT[jchunk=4][cc=256][8]: PV B-read = 16B/lane, cc lane-consecutive.
__global__ __launch_bounds__(256, 2) void k_attn(
    const short* __restrict__ phiB, const short* __restrict__ thetaB,
    const short* __restrict__ gB, float* __restrict__ omidP) {
  __shared__ short phiT[2][32 * 128];
  __shared__ short gT[2][4 * 256 * 8];   // [jchunk][cc][8]
  __shared__ short pT[4][16 * 32];
  const int tid = threadIdx.x, lane = tid & 63, w = tid >> 6;
  const int x = lane & 15, q = lane >> 4;
  const int i0 = blockIdx.x * 64, jh = blockIdx.y, b = blockIdx.z;
  const short* phb = phiB + (size_t)b * NPOS * NCI;
  const short* thb = thetaB + (size_t)b * NPOS * NCI;
  const short* gb = gB + (size_t)b * NC * NPOS;
  float* om = omidP + ((size_t)(jh * NB + b)) * NC * NPOS;

  bf16x8 tf[4];
  {
    const short* tr = thb + (size_t)(i0 + w * 16 + x) * NCI;
#pragma unroll
    for (int kk = 0; kk < 4; ++kk) tf[kk] = *(const bf16x8*)(tr + kk * 32 + q * 8);
  }
  f32x4 acc[16];
#pragma unroll
  for (int i = 0; i < 16; ++i) acc[i] = (f32x4){0.f, 0.f, 0.f, 0.f};

  int4 rphi[2], rg[4];
  const int NT = 64;
  const int jbase = jh * 64;
#define ATTN_LOAD(jt)                                                          \
  { _Pragma("unroll") for (int r = 0; r < 2; ++r) {                            \
      int s = tid + r * 256; int row = s >> 4, c = s & 15;                     \
      rphi[r] = *(const int4*)(phb + (size_t)((jbase + (jt)) * 32 + row) * NCI + c * 8); } \
    _Pragma("unroll") for (int r = 0; r < 4; ++r) {                            \
      int s = tid + r * 256; int cc = s >> 2, c4 = s & 3;                      \
      rg[r] = *(const int4*)(gb + (size_t)cc * NPOS + (jbase + (jt)) * 32 + c4 * 8); } }
#define ATTN_WRITE(buf)                                                        \
  { _Pragma("unroll") for (int r = 0; r < 2; ++r) {                            \
      int s = tid + r * 256; int row = s >> 4, c = s & 15;                     \
      *(int4*)(&phiT[buf][row * 128 + ((c ^ (row & 7)) * 8)]) = rphi[r]; }     \
    _Pragma("unroll") for (int r = 0; r < 4; ++r) {                            \
      int s = tid + r * 256; int cc = s >> 2, c4 = s & 3;                      \
      *(int4*)(&gT[buf][c4 * 2048 + cc * 8]) = rg[r]; } }
  ATTN_LOAD(0); ATTN_WRITE(0); __syncthreads();
  int cur = 0;
  for (int jt = 0; jt < NT; ++jt) {
    if (jt + 1 < NT) ATTN_LOAD(jt + 1);
    {
      const short* PH = &phiT[cur][0];
      const short* GT = &gT[cur][0];
      short* PW = &pT[w][0];
#pragma unroll
      for (int jsub = 0; jsub < 2; ++jsub) {
        f32x4 s = {0.f, 0.f, 0.f, 0.f};
        int row = jsub * 16 + x;
        int sw = row & 7;
#pragma unroll
        for (int kk = 0; kk < 4; ++kk) {
          bf16x8 a = *(const bf16x8*)(PH + row * 128 + (((kk * 4 + q) ^ sw) * 8));
          s = __builtin_amdgcn_mfma_f32_16x16x32_bf16(a, tf[kk], s, 0, 0, 0);
        }
        unsigned short p0 = f2bf(__expf(s[0]));
        unsigned short p1 = f2bf(__expf(s[1]));
        unsigned short p2 = f2bf(__expf(s[2]));
        unsigned short p3 = f2bf(__expf(s[3]));
        unsigned int lo = (unsigned int)p0 | ((unsigned int)p1 << 16);
        unsigned int hi = (unsigned int)p2 | ((unsigned int)p3 << 16);
        int byteoff = (x * 64 + jsub * 32 + q * 8) ^ ((((x >> 1) & 3)) << 4);
        *(uint2*)((char*)PW + byteoff) = make_uint2(lo, hi);
      }
      {
        int c = q ^ ((x >> 1) & 3);
        bf16x8 ap = *(const bf16x8*)((const char*)PW + x * 64 + c * 16);
#pragma unroll
        for (int cf = 0; cf < 16; ++cf) {
          bf16x8 bg = *(const bf16x8*)(GT + q * 2048 + (cf * 16 + x) * 8);
          acc[cf] = __builtin_amdgcn_mfma_f32_16x16x32_bf16(ap, bg, acc[cf], 0, 0, 0);
        }
      }
    }
    if (jt + 1 < NT) ATTN_WRITE(cur ^ 1);
    __syncthreads();
    cur ^= 1;
  }
#pragma unroll
  for (int cf = 0; cf < 16; ++cf) {
    size_t o = (size_t)(cf * 16 + x) * NPOS + i0 + w * 16 + 4 * q;
    *reinterpret_cast<f32x4*>(&om[o]) = acc[cf];
  }
#undef ATTN_LOAD
#undef ATTN_WRITE
}

extern "C" void kernel_launch(void* const* d_in, const int* in_sizes, int n_in,
                              void* d_out, int out_size, void* d_ws, size_t ws_size,
                              hipStream_t stream) {
  (void)in_sizes; (void)n_in; (void)out_size; (void)ws_size;
  const float* x0      = (const float*)d_in[0];
  const float* x       = (const float*)d_in[1];
  const float* x_dsm   = (const float*)d_in[2];
  const float* w_phi   = (const float*)d_in[3];
  const float* w_theta = (const float*)d_in[4];
  const float* w_g     = (const float*)d_in[5];
  const float* w_mask  = (const float*)d_in[6];
  float* outp = (float*)d_out;

  short* sp = (short*)d_ws;
  short* wb_phi   = sp; sp += 32768;
  short* wb_theta = sp; sp += 32768;
  short* wb_g     = sp; sp += 131072;
  short* wb_mask  = sp; sp += 131072;
  short* xT   = sp; sp += (size_t)NB * NPOS * NC;
  short* xdT  = sp; sp += (size_t)NB * NPOS * NC;
  short* x0T  = sp; sp += (size_t)NB * NPOS * NC2;
  short* phiB   = sp; sp += (size_t)NB * NPOS * NCI;
  short* thetaB = sp; sp += (size_t)NB * NPOS * NCI;
  short* gBuf   = sp; sp += (size_t)NB * NC * NPOS;
  float* linv = (float*)sp; sp += 2 * (size_t)NB * NPOS;
  float* plsum = (float*)sp;                               // [b][ISPLIT][NPOS]
  float* omidP = (float*)xT;
  short* omidT = phiB;

  k_cast4<<<dim3(1280), 256, 0, stream>>>(w_phi, wb_phi, 32768,
                                          w_theta, wb_theta, 32768,
                                          w_g, wb_g, 131072,
                                          w_mask, wb_mask, 131072);

  k_tcast<<<dim3(64, 4, NB), 256, 0, stream>>>(x, xT, NC, NPOS,
      (size_t)NC * NPOS, (size_t)NPOS * NC);
  k_tcast<<<dim3(64, 4, NB), 256, 0, stream>>>(x_dsm, xdT, NC, NPOS,
      (size_t)NC * NPOS, (size_t)NPOS * NC);
  k_tcast<<<dim3(64, 8, NB), 256, 0, stream>>>(x0, x0T, NC2, NPOS,
      (size_t)NC2 * NPOS, (size_t)NPOS * NC2);

  k_gemm<true, false><<<dim3(64, 2, NB), 256, 0, stream>>>(
      wb_phi, xT, phiB, nullptr, NC, NCI, 0, (size_t)NPOS * NC, (size_t)NPOS * NCI);
  k_gemm<true, false><<<dim3(64, 2, NB), 256, 0, stream>>>(
      wb_theta, xdT, thetaB, nullptr, NC, NCI, 0, (size_t)NPOS * NC, (size_t)NPOS * NCI);
  k_gemm<true, false><<<dim3(4, 64, NB), 256, 0, stream>>>(
      x0T, wb_g, gBuf, nullptr, NC2, NPOS, (size_t)NPOS * NC2, 0, (size_t)NC * NPOS);

  k_lsum<<<dim3(NPOS / 64, ISPLIT, NB), 256, 0, stream>>>(phiB, thetaB, plsum);
  k_lcomb<<<dim3(NB * NPOS / 256), 256, 0, stream>>>(plsum, linv);
  k_scale_g<<<dim3(2048), 256, 0, stream>>>(gBuf, linv);

  k_attn<<<dim3(64, 2, NB), 256, 0, stream>>>(phiB, thetaB, gBuf, omidP);

  k_tcast2<<<dim3(64, 4, NB), 256, 0, stream>>>(omidP, omidP + (size_t)NB * NC * NPOS,
      omidT, NC, NPOS, (size_t)NC * NPOS, (size_t)NPOS * NC);

  k_gemm<false, true><<<dim3(8, 64, NB), 256, 0, stream>>>(
      omidT, wb_mask, outp, x0, NC, NPOS, (size_t)NPOS * NC, 0, (size_t)NC2 * NPOS);
}